// Round 5
// baseline (163.199 us; speedup 1.0000x reference)
//
#include <hip/hip_runtime.h>
#include <cstddef>
#include <cstdint>

// ---------------------------------------------------------------------------
// x [N=32, C=256, H=64, W=64] fp32. Branches: sq 3x3 pad(1,1) ch 64..127,
// ver 3x1 pad(1,0) ch 128..191, hor 1x3 pad(0,1) ch 192..255. CondConv K=4.
// Training-mode BN per branch, concat(s0,sq,ve,ho), channel_shuffle(g=8):
//   c_out = (c_pre % 32)*8 + c_pre/32
// Conv: per-sample GEMM on matrix cores, bf16 in / fp32 accum.
// Round 5: prepass converts x to bf16 in the EXACT conv-LDS tile layout
// ([n][padded row][chunk][66 w-slots][8ch]), halos pre-zeroed, fused with
// the pool reduction. Conv staging = contiguous global_load_lds DMA
// (no VALU packing, no register round-trip, no bounds logic).
// ---------------------------------------------------------------------------

typedef __attribute__((ext_vector_type(8))) short frag8;    // 8 bf16 = 4 VGPR
typedef __attribute__((ext_vector_type(16))) float accf16;  // 32x32 accum

#define HW 4096
#define CNT_INV (1.0f / 131072.0f)
#define CSTR 1056                 // chunk stride bytes: 66 slots * 16
#define RSTR 8448                 // row stride bytes: 8 chunks * CSTR
#define XT_BR (32ull * 66 * 8448) // bytes per branch of transposed x

// workspace offsets (4-byte units)
#define WS_POOLED 0            // 6144
#define WS_ATT    6144         // 384
#define WS_SS     6528         // 384 (3 * 128)
#define WS_PST    6912         // 3 * 65536
#define WS_WBF_SQ  203520      // 589824 u32 (bf16 pairs)
#define WS_WBF_VER 793344      // 196608
#define WS_WBF_HOR 989952      // 196608
#define WS_XT      1186560     // 3 * XT_BR bytes (+512B slack)

__device__ __forceinline__ int shuf_ch(int c) { return ((c & 31) << 3) | (c >> 5); }

__device__ __forceinline__ unsigned bf16pair(float a, float b) {
    unsigned ua = __builtin_bit_cast(unsigned, a);
    unsigned ub = __builtin_bit_cast(unsigned, b);
    ua = (ua + 0x7fffu + ((ua >> 16) & 1u)) >> 16;   // round-to-nearest-even
    ub = (ub + 0x7fffu + ((ub >> 16) & 1u)) >> 16;
    return ua | (ub << 16);
}

__device__ __forceinline__ void gload_lds16(const void* g, void* l) {
    __builtin_amdgcn_global_load_lds(
        (const __attribute__((address_space(1))) void*)g,
        (__attribute__((address_space(3))) void*)l, 16, 0, 0);
}

// ---- 1. prepass: pool + bf16 transpose into conv tile layout ---------------
__global__ void __launch_bounds__(256) prepass_kernel(
    const float* __restrict__ x, unsigned char* __restrict__ xt,
    float* __restrict__ pooled) {
    const int bid = blockIdx.x;           // (b*32+n)*8 + c8, 768 blocks
    const int c8 = bid & 7;
    const int n = (bid >> 3) & 31;
    const int b = bid >> 8;
    const int tid = threadIdx.x;
    const int w = tid & 63, q = tid >> 6;
    const float* xb = x + (size_t)(n * 256 + 64 * (b + 1) + c8 * 8) * HW;
    unsigned char* xtb = xt + (size_t)b * XT_BR + (size_t)n * 66 * RSTR + c8 * CSTR;

    float ps[8] = {0.f, 0.f, 0.f, 0.f, 0.f, 0.f, 0.f, 0.f};
    for (int h = q; h < 64; h += 4) {
        float v[8];
#pragma unroll
        for (int j = 0; j < 8; ++j) v[j] = xb[(size_t)j * HW + h * 64 + w];
        unsigned pk[4];
#pragma unroll
        for (int j = 0; j < 4; ++j) pk[j] = bf16pair(v[2 * j], v[2 * j + 1]);
        *(uint4*)(xtb + (size_t)(h + 1) * RSTR + (w + 1) * 16) = *(uint4*)pk;
#pragma unroll
        for (int j = 0; j < 8; ++j) ps[j] += v[j];
    }
    // zero halo: rows 0,65 (all 66 slots); rows 1..64 slots 0,65
    for (int idx = tid; idx < 260; idx += 256) {
        int p, slot;
        if (idx < 66)       { p = 0;         slot = idx; }
        else if (idx < 132) { p = 65;        slot = idx - 66; }
        else if (idx < 196) { p = idx - 131; slot = 0; }
        else                { p = idx - 195; slot = 65; }
        *(uint4*)(xtb + (size_t)p * RSTR + slot * 16) = uint4{0, 0, 0, 0};
    }
    // pool reduce
    __shared__ float red[4][8];
#pragma unroll
    for (int j = 0; j < 8; ++j)
#pragma unroll
        for (int off = 32; off; off >>= 1) ps[j] += __shfl_down(ps[j], off, 64);
    if ((tid & 63) == 0)
#pragma unroll
        for (int j = 0; j < 8; ++j) red[q][j] = ps[j];
    __syncthreads();
    if (tid < 8)
        pooled[(b * 32 + n) * 64 + c8 * 8 + tid] =
            (red[0][tid] + red[1][tid] + red[2][tid] + red[3][tid]) * (1.f / 4096.f);
}

// ---- 2. attention, all 3 branches: 96 blocks x 64 threads ------------------
__global__ void __launch_bounds__(64) att_all_kernel(
    const float* __restrict__ pooled,
    const float* __restrict__ aw0, const float* __restrict__ ab0,
    const float* __restrict__ aw1, const float* __restrict__ ab1,
    const float* __restrict__ aw2, const float* __restrict__ ab2,
    float* __restrict__ att) {
    int bid = blockIdx.x;                 // b*32+n
    int b = bid >> 5;
    const float* aw = (b == 0) ? aw0 : (b == 1) ? aw1 : aw2;
    const float* ab = (b == 0) ? ab0 : (b == 1) ? ab1 : ab2;
    int t = threadIdx.x;
    float p = pooled[bid * 64 + t];
#pragma unroll
    for (int k = 0; k < 4; ++k) {
        float v = p * aw[k * 64 + t];
#pragma unroll
        for (int off = 32; off; off >>= 1) v += __shfl_down(v, off, 64);
        if (t == 0) att[bid * 4 + k] = 1.f / (1.f + expf(-(v + ab[k])));
    }
}

// ---- 3. expert-mix weights -> bf16, layout [n][tap][o][i] ------------------
template <int TAPS>
__device__ __forceinline__ void aggbf_body(const float* __restrict__ w,
                                           const float* __restrict__ att,
                                           unsigned* __restrict__ wbf, int bid) {
    int idx = bid * 256 + threadIdx.x;            // ((n*TAPS+t)*64+o)*32+ip
    int ip = idx & 31;
    int o  = (idx >> 5) & 63;
    int t  = (idx >> 11) % TAPS;
    int n  = (idx >> 11) / TAPS;
    const float* a = att + n * 4;
    constexpr int PS = 64 * 64 * TAPS;
    int base = (o * 64 + ip * 2) * TAPS + t;      // w[k][o][i][t]
    float v0 = a[0]*w[base] + a[1]*w[PS+base] + a[2]*w[2*PS+base] + a[3]*w[3*PS+base];
    int base1 = base + TAPS;
    float v1 = a[0]*w[base1] + a[1]*w[PS+base1] + a[2]*w[2*PS+base1] + a[3]*w[3*PS+base1];
    wbf[idx] = bf16pair(v0, v1);
}

__global__ void __launch_bounds__(256) aggbf_all_kernel(
    const float* __restrict__ sq_w, const float* __restrict__ ver_w,
    const float* __restrict__ hor_w, const float* __restrict__ att,
    unsigned* __restrict__ wsq, unsigned* __restrict__ wver,
    unsigned* __restrict__ whor) {
    int bid = blockIdx.x;
    if (bid < 2304)      aggbf_body<9>(sq_w,  att,       wsq,  bid);
    else if (bid < 3072) aggbf_body<3>(ver_w, att + 128, wver, bid - 2304);
    else                 aggbf_body<3>(hor_w, att + 256, whor, bid - 3072);
}

// ---- 4. fused conv (3 branches) + s0 copy ----------------------------------
template <int KH, int KW, int PH, int PW>
__device__ __forceinline__ void conv_body(
    const unsigned char* __restrict__ xt, const unsigned* __restrict__ wbf,
    float* __restrict__ out, float* __restrict__ pst, int cbase, int bid,
    unsigned char* xs, float (*red1)[2][2][16], float (*red2)[2][2][16]) {
    constexpr int TAPS = KH * KW;
    constexpr int HB = 4;
    constexpr int ROWS = HB + KH - 1;
    constexpr int TOT = ROWS * RSTR;
    constexpr int NCH = (TOT + 1023) >> 10;   // 50 (KH=3) / 33 (KH=1)
    const int hb = bid & 15, n = bid >> 4;
    const int h0 = hb * HB;
    const int tid = threadIdx.x;
    const int lane = tid & 63;
    const int wv = tid >> 6;
    const int rh = wv >> 1, wn = wv & 1;  // wave = (row-half, w-half)
    const int l31 = lane & 31, hi = lane >> 5;
    const int wcol = wn * 32 + l31;

    // DMA-stage ROWS rows (contiguous span, pre-transposed, halos pre-zeroed)
    {
        const unsigned char* src = xt +
            (size_t)(n * 66 + h0 + (KH == 1 ? 1 : 0)) * RSTR + lane * 16;
#pragma unroll
        for (int c = wv; c < NCH; c += 4)
            gload_lds16(src + (c << 10), xs + (c << 10));
    }

    // A fragments: frag f=kk*2+hi of row o, tap t at wp[t*512 + wm*256 + kk*2]
    const frag8* wp = (const frag8*)wbf + ((size_t)n * TAPS * 64 + l31) * 8 + hi;

    __syncthreads();

    accf16 a00 = {}, a01 = {}, a10 = {}, a11 = {};   // a{wm}{row}
#pragma unroll
    for (int t = 0; t < TAPS; ++t) {
        const int r_ = t / KW, dw = t % KW - PW;
        frag8 af[8];
#pragma unroll
        for (int kk = 0; kk < 4; ++kk) {
            af[kk]     = wp[t * 512 + kk * 2];
            af[4 + kk] = wp[t * 512 + 256 + kk * 2];
        }
        const unsigned char* bp = xs + (rh * 2 + r_) * RSTR + hi * CSTR +
                                  (wcol + dw + 1) * 16;
#pragma unroll
        for (int kk = 0; kk < 4; ++kk) {
            frag8 b0 = *(const frag8*)(bp + kk * 2 * CSTR);
            frag8 b1 = *(const frag8*)(bp + kk * 2 * CSTR + RSTR);
            a00 = __builtin_amdgcn_mfma_f32_32x32x16_bf16(af[kk],     b0, a00, 0, 0, 0);
            a10 = __builtin_amdgcn_mfma_f32_32x32x16_bf16(af[4 + kk], b0, a10, 0, 0, 0);
            a01 = __builtin_amdgcn_mfma_f32_32x32x16_bf16(af[kk],     b1, a01, 0, 0, 0);
            a11 = __builtin_amdgcn_mfma_f32_32x32x16_bf16(af[4 + kk], b1, a11, 0, 0, 0);
        }
    }

    // C write: rows h0+rh*2, h0+rh*2+1; both o-halves
    {
        float* ob = out + (size_t)n * 256 * HW + (h0 + rh * 2) * 64 + wcol;
#pragma unroll
        for (int rg = 0; rg < 16; ++rg) {
            const int o = (rg & 3) + 8 * (rg >> 2) + 4 * hi;
            float* p0 = ob + (size_t)shuf_ch(cbase + o) * HW;
            p0[0]  = a00[rg];
            p0[64] = a01[rg];
            float* p1 = ob + (size_t)shuf_ch(cbase + 32 + o) * HW;
            p1[0]  = a10[rg];
            p1[64] = a11[rg];
        }
    }

    // BN partial sums
#pragma unroll
    for (int rg = 0; rg < 16; ++rg) {
        float u1 = a00[rg] + a01[rg];
        float u2 = a00[rg] * a00[rg] + a01[rg] * a01[rg];
        float w1 = a10[rg] + a11[rg];
        float w2 = a10[rg] * a10[rg] + a11[rg] * a11[rg];
#pragma unroll
        for (int off = 16; off; off >>= 1) {
            u1 += __shfl_down(u1, off, 32);
            u2 += __shfl_down(u2, off, 32);
            w1 += __shfl_down(w1, off, 32);
            w2 += __shfl_down(w2, off, 32);
        }
        if (l31 == 0) {
            red1[wv][0][hi][rg] = u1; red2[wv][0][hi][rg] = u2;
            red1[wv][1][hi][rg] = w1; red2[wv][1][hi][rg] = w2;
        }
    }
    __syncthreads();
    if (tid < 64) {
        const int rg = tid & 15, hi2 = (tid >> 4) & 1, wm2 = tid >> 5;
        float s1 = 0.f, s2 = 0.f;
#pragma unroll
        for (int v = 0; v < 4; ++v) {
            s1 += red1[v][wm2][hi2][rg];
            s2 += red2[v][wm2][hi2][rg];
        }
        const int o = wm2 * 32 + (rg & 3) + 8 * (rg >> 2) + 4 * hi2;
        const int slot = n * 16 + hb;
        pst[o * 1024 + slot] = s1;
        pst[o * 1024 + 512 + slot] = s2;
    }
}

__device__ __forceinline__ void s0_body(const float* __restrict__ x,
                                        float* __restrict__ out, int bid) {
    const int n = bid >> 4, c0 = (bid & 15) * 4, tid = threadIdx.x;
#pragma unroll
    for (int j = 0; j < 4; ++j) {
        const int c = c0 + j;
        const float4* s = (const float4*)(x + (size_t)(n * 256 + c) * HW);
        float4* d = (float4*)(out + (size_t)(n * 256 + shuf_ch(c)) * HW);
#pragma unroll
        for (int it = 0; it < 4; ++it) d[tid + it * 256] = s[tid + it * 256];
    }
}

__global__ void __launch_bounds__(256, 3) conv_all_kernel(
    const float* __restrict__ x, const unsigned char* __restrict__ xt,
    const unsigned* __restrict__ wsq, const unsigned* __restrict__ wver,
    const unsigned* __restrict__ whor,
    float* __restrict__ out, float* __restrict__ pst) {
    __shared__ __align__(16) unsigned char xs[6 * RSTR + 512];
    __shared__ float red1[4][2][2][16], red2[4][2][2][16];
    int bid = blockIdx.x;
    if (bid < 512)
        conv_body<3, 3, 1, 1>(xt, wsq, out, pst, 64, bid, xs, red1, red2);
    else if (bid < 1024)
        conv_body<3, 1, 1, 0>(xt + XT_BR, wver, out, pst + 65536, 128,
                              bid - 512, xs, red1, red2);
    else if (bid < 1536)
        conv_body<1, 3, 0, 1>(xt + 2 * XT_BR, whor, out, pst + 131072, 192,
                              bid - 1024, xs, red1, red2);
    else
        s0_body(x, out, bid - 1536);
}

// ---- 5. reduce BN partials -> scale/shift, all branches --------------------
__global__ void __launch_bounds__(256) bnstats_all_kernel(
    const float* __restrict__ pst,
    const float* __restrict__ g0, const float* __restrict__ b0,
    const float* __restrict__ g1, const float* __restrict__ b1,
    const float* __restrict__ g2, const float* __restrict__ b2,
    float* __restrict__ ss) {
    int br = blockIdx.x >> 6, o = blockIdx.x & 63, t = threadIdx.x;
    const float* gamma = (br == 0) ? g0 : (br == 1) ? g1 : g2;
    const float* beta  = (br == 0) ? b0 : (br == 1) ? b1 : b2;
    const float* p = pst + br * 65536 + o * 1024;
    float s1 = 0.f, s2 = 0.f;
    for (int i = t; i < 512; i += 256) {
        s1 += p[i];
        s2 += p[512 + i];
    }
#pragma unroll
    for (int off = 32; off; off >>= 1) {
        s1 += __shfl_down(s1, off, 64);
        s2 += __shfl_down(s2, off, 64);
    }
    __shared__ float r1[4], r2[4];
    if ((t & 63) == 0) { r1[t >> 6] = s1; r2[t >> 6] = s2; }
    __syncthreads();
    if (t == 0) {
        float S1 = r1[0] + r1[1] + r1[2] + r1[3];
        float S2 = r2[0] + r2[1] + r2[2] + r2[3];
        float mean = S1 * CNT_INV;
        float var = S2 * CNT_INV - mean * mean;
        float scale = rsqrtf(var + 1e-5f) * gamma[o];
        ss[br * 128 + o * 2 + 0] = scale;
        ss[br * 128 + o * 2 + 1] = beta[o] - mean * scale;
    }
}

// ---- 6. apply BN in-place on d_out, all branches ---------------------------
__global__ void __launch_bounds__(256) bn_all_kernel(float* __restrict__ out,
                                                     const float* __restrict__ ss) {
    int gbid = blockIdx.x;                // 3 * 8192
    int sub = gbid >> 13;
    int bid = gbid & 8191;
    int chunk = bid & 3;
    int n = (bid >> 2) & 31;
    int o = bid >> 7;
    float scale = ss[sub * 128 + o * 2], shift = ss[sub * 128 + o * 2 + 1];
    int c_out = shuf_ch(64 * (sub + 1) + o);
    float4* p = (float4*)(out + (size_t)(n * 256 + c_out) * HW) + chunk * 256 + threadIdx.x;
    float4 v = *p;
    v.x = fmaf(v.x, scale, shift);
    v.y = fmaf(v.y, scale, shift);
    v.z = fmaf(v.z, scale, shift);
    v.w = fmaf(v.w, scale, shift);
    *p = v;
}

extern "C" void kernel_launch(void* const* d_in, const int* in_sizes, int n_in,
                              void* d_out, int out_size, void* d_ws, size_t ws_size,
                              hipStream_t stream) {
    const float* x        = (const float*)d_in[0];
    const float* sq_att_w = (const float*)d_in[1];
    const float* sq_att_b = (const float*)d_in[2];
    const float* sq_w     = (const float*)d_in[3];
    const float* sq_g     = (const float*)d_in[4];
    const float* sq_b     = (const float*)d_in[5];
    const float* ver_att_w= (const float*)d_in[6];
    const float* ver_att_b= (const float*)d_in[7];
    const float* ver_w    = (const float*)d_in[8];
    const float* ver_g    = (const float*)d_in[9];
    const float* ver_b    = (const float*)d_in[10];
    const float* hor_att_w= (const float*)d_in[11];
    const float* hor_att_b= (const float*)d_in[12];
    const float* hor_w    = (const float*)d_in[13];
    const float* hor_g    = (const float*)d_in[14];
    const float* hor_b    = (const float*)d_in[15];
    float* out = (float*)d_out;
    float* ws = (float*)d_ws;

    float* pooled = ws + WS_POOLED;
    float* att    = ws + WS_ATT;
    float* ss     = ws + WS_SS;
    float* pst    = ws + WS_PST;
    unsigned* wbf_sq  = (unsigned*)(ws + WS_WBF_SQ);
    unsigned* wbf_ver = (unsigned*)(ws + WS_WBF_VER);
    unsigned* wbf_hor = (unsigned*)(ws + WS_WBF_HOR);
    unsigned char* xt = (unsigned char*)(ws + WS_XT);

    prepass_kernel<<<768, 256, 0, stream>>>(x, xt, pooled);
    att_all_kernel<<<96, 64, 0, stream>>>(pooled, sq_att_w, sq_att_b,
                                          ver_att_w, ver_att_b,
                                          hor_att_w, hor_att_b, att);
    aggbf_all_kernel<<<3840, 256, 0, stream>>>(sq_w, ver_w, hor_w, att,
                                               wbf_sq, wbf_ver, wbf_hor);
    conv_all_kernel<<<2048, 256, 0, stream>>>(x, xt, wbf_sq, wbf_ver, wbf_hor,
                                              out, pst);
    bnstats_all_kernel<<<192, 256, 0, stream>>>(pst, sq_g, sq_b, ver_g, ver_b,
                                                hor_g, hor_b, ss);
    bn_all_kernel<<<24576, 256, 0, stream>>>(out, ss);
}

// Round 6
// 156.151 us; speedup vs baseline: 1.0451x; 1.0451x over previous
//
#include <hip/hip_runtime.h>
#include <cstddef>
#include <cstdint>

// ---------------------------------------------------------------------------
// x [N=32, C=256, H=64, W=64] fp32. Branches: sq 3x3 pad(1,1) ch 64..127,
// ver 3x1 pad(1,0) ch 128..191, hor 1x3 pad(0,1) ch 192..255. CondConv K=4.
// Training-mode BN per branch, concat(s0,sq,ve,ho), channel_shuffle(g=8):
//   c_out = (c_pre % 32)*8 + c_pre/32
// Conv: per-sample GEMM on matrix cores, bf16 in / fp32 accum.
// Round 6: (1) weight layout [n][tap][frag][o] -> wave A-loads are contiguous
// (2 x 512B runs, was 64 cache lines); (2) explicit depth-1 A double-buffer
// so A-loads overlap the 16-MFMA tap body; (3) att fused into aggbf.
// ---------------------------------------------------------------------------

typedef __attribute__((ext_vector_type(8))) short frag8;    // 8 bf16 = 4 VGPR
typedef __attribute__((ext_vector_type(16))) float accf16;  // 32x32 accum

#define HW 4096
#define CNT_INV (1.0f / 131072.0f)
#define CSTR 1056                 // chunk stride bytes: 66 slots * 16
#define RSTR 8448                 // row stride bytes: 8 chunks * CSTR
#define XT_BR (32ull * 66 * 8448) // bytes per branch of transposed x

// workspace offsets (4-byte units)
#define WS_POOLED 0            // 6144
#define WS_SS     6528         // 384 (3 * 128)
#define WS_PST    6912         // 3 * 65536
#define WS_WBF_SQ  203520      // 589824 u32 (bf16 pairs)
#define WS_WBF_VER 793344      // 196608
#define WS_WBF_HOR 989952      // 196608
#define WS_XT      1186560     // 3 * XT_BR bytes (+512B slack)

__device__ __forceinline__ int shuf_ch(int c) { return ((c & 31) << 3) | (c >> 5); }

__device__ __forceinline__ unsigned bf16pair(float a, float b) {
    unsigned ua = __builtin_bit_cast(unsigned, a);
    unsigned ub = __builtin_bit_cast(unsigned, b);
    ua = (ua + 0x7fffu + ((ua >> 16) & 1u)) >> 16;   // round-to-nearest-even
    ub = (ub + 0x7fffu + ((ub >> 16) & 1u)) >> 16;
    return ua | (ub << 16);
}

__device__ __forceinline__ void gload_lds16(const void* g, void* l) {
    __builtin_amdgcn_global_load_lds(
        (const __attribute__((address_space(1))) void*)g,
        (__attribute__((address_space(3))) void*)l, 16, 0, 0);
}

// ---- 1. prepass: pool + bf16 transpose into conv tile layout ---------------
__global__ void __launch_bounds__(256) prepass_kernel(
    const float* __restrict__ x, unsigned char* __restrict__ xt,
    float* __restrict__ pooled) {
    const int bid = blockIdx.x;           // (b*32+n)*8 + c8, 768 blocks
    const int c8 = bid & 7;
    const int n = (bid >> 3) & 31;
    const int b = bid >> 8;
    const int tid = threadIdx.x;
    const int w = tid & 63, q = tid >> 6;
    const float* xb = x + (size_t)(n * 256 + 64 * (b + 1) + c8 * 8) * HW;
    unsigned char* xtb = xt + (size_t)b * XT_BR + (size_t)n * 66 * RSTR + c8 * CSTR;

    float ps[8] = {0.f, 0.f, 0.f, 0.f, 0.f, 0.f, 0.f, 0.f};
    for (int h = q; h < 64; h += 4) {
        float v[8];
#pragma unroll
        for (int j = 0; j < 8; ++j) v[j] = xb[(size_t)j * HW + h * 64 + w];
        unsigned pk[4];
#pragma unroll
        for (int j = 0; j < 4; ++j) pk[j] = bf16pair(v[2 * j], v[2 * j + 1]);
        *(uint4*)(xtb + (size_t)(h + 1) * RSTR + (w + 1) * 16) = *(uint4*)pk;
#pragma unroll
        for (int j = 0; j < 8; ++j) ps[j] += v[j];
    }
    // zero halo: rows 0,65 (all 66 slots); rows 1..64 slots 0,65
    for (int idx = tid; idx < 260; idx += 256) {
        int p, slot;
        if (idx < 66)       { p = 0;         slot = idx; }
        else if (idx < 132) { p = 65;        slot = idx - 66; }
        else if (idx < 196) { p = idx - 131; slot = 0; }
        else                { p = idx - 195; slot = 65; }
        *(uint4*)(xtb + (size_t)p * RSTR + slot * 16) = uint4{0, 0, 0, 0};
    }
    // pool reduce
    __shared__ float red[4][8];
#pragma unroll
    for (int j = 0; j < 8; ++j)
#pragma unroll
        for (int off = 32; off; off >>= 1) ps[j] += __shfl_down(ps[j], off, 64);
    if ((tid & 63) == 0)
#pragma unroll
        for (int j = 0; j < 8; ++j) red[q][j] = ps[j];
    __syncthreads();
    if (tid < 8)
        pooled[(b * 32 + n) * 64 + c8 * 8 + tid] =
            (red[0][tid] + red[1][tid] + red[2][tid] + red[3][tid]) * (1.f / 4096.f);
}

// ---- 2. expert-mix weights -> bf16, layout [n][tap][frag][o][4u32] ---------
// att computed inline (n is uniform per block).
template <int TAPS>
__device__ __forceinline__ void aggbf_body(const float* __restrict__ w,
                                           const float* __restrict__ pooled_b,
                                           const float* __restrict__ aw,
                                           const float* __restrict__ ab,
                                           unsigned* __restrict__ wbf, int bid) {
    const int tid = threadIdx.x;
    int idx = bid * 256 + tid;                    // (n*TAPS+t)*2048 + o*32 + ip
    int ip = idx & 31;
    int o  = (idx >> 5) & 63;
    int t  = (idx >> 11) % TAPS;
    int n  = (idx >> 11) / TAPS;

    __shared__ float satt[4];
    if (tid < 64) {
        float p = pooled_b[n * 64 + tid];
#pragma unroll
        for (int k = 0; k < 4; ++k) {
            float v = p * aw[k * 64 + tid];
#pragma unroll
            for (int off = 32; off; off >>= 1) v += __shfl_down(v, off, 64);
            if (tid == 0) satt[k] = 1.f / (1.f + expf(-(v + ab[k])));
        }
    }
    __syncthreads();
    const float a0 = satt[0], a1 = satt[1], a2 = satt[2], a3 = satt[3];

    constexpr int PS = 64 * 64 * TAPS;
    int base = (o * 64 + ip * 2) * TAPS + t;      // w[k][o][i][t]
    float v0 = a0*w[base] + a1*w[PS+base] + a2*w[2*PS+base] + a3*w[3*PS+base];
    int base1 = base + TAPS;
    float v1 = a0*w[base1] + a1*w[PS+base1] + a2*w[2*PS+base1] + a3*w[3*PS+base1];
    // new coalesced layout: u32 idx = (((n*T+t)*8 + f)*64 + o)*4 + jj
    int f = ip >> 2, jj = ip & 3;
    wbf[(((n * TAPS + t) * 8 + f) * 64 + o) * 4 + jj] = bf16pair(v0, v1);
}

__global__ void __launch_bounds__(256) aggbf_all_kernel(
    const float* __restrict__ pooled,
    const float* __restrict__ aw0, const float* __restrict__ ab0,
    const float* __restrict__ aw1, const float* __restrict__ ab1,
    const float* __restrict__ aw2, const float* __restrict__ ab2,
    const float* __restrict__ sq_w, const float* __restrict__ ver_w,
    const float* __restrict__ hor_w,
    unsigned* __restrict__ wsq, unsigned* __restrict__ wver,
    unsigned* __restrict__ whor) {
    int bid = blockIdx.x;
    if (bid < 2304)
        aggbf_body<9>(sq_w, pooled, aw0, ab0, wsq, bid);
    else if (bid < 3072)
        aggbf_body<3>(ver_w, pooled + 2048, aw1, ab1, wver, bid - 2304);
    else
        aggbf_body<3>(hor_w, pooled + 4096, aw2, ab2, whor, bid - 3072);
}

// ---- 3. fused conv (3 branches) + s0 copy ----------------------------------
#define LOADA(dst, tt) \
    _Pragma("unroll") for (int kk = 0; kk < 4; ++kk) { \
        dst[kk]     = wp[(tt) * 512 + kk * 128]; \
        dst[4 + kk] = wp[(tt) * 512 + kk * 128 + 32]; \
    }

#define TAPSTEP(tt, CUR) { \
    const int r_ = (tt) / KW, dw_ = (tt) % KW - PW; \
    const unsigned char* bp_ = xs + (rh * 2 + r_) * RSTR + hi * CSTR + \
                               (wcol + dw_ + 1) * 16; \
    _Pragma("unroll") for (int kk = 0; kk < 4; ++kk) { \
        frag8 b0 = *(const frag8*)(bp_ + kk * 2 * CSTR); \
        frag8 b1 = *(const frag8*)(bp_ + kk * 2 * CSTR + RSTR); \
        a00 = __builtin_amdgcn_mfma_f32_32x32x16_bf16(CUR[kk],     b0, a00, 0, 0, 0); \
        a10 = __builtin_amdgcn_mfma_f32_32x32x16_bf16(CUR[4 + kk], b0, a10, 0, 0, 0); \
        a01 = __builtin_amdgcn_mfma_f32_32x32x16_bf16(CUR[kk],     b1, a01, 0, 0, 0); \
        a11 = __builtin_amdgcn_mfma_f32_32x32x16_bf16(CUR[4 + kk], b1, a11, 0, 0, 0); \
    } }

template <int KH, int KW, int PH, int PW>
__device__ __forceinline__ void conv_body(
    const unsigned char* __restrict__ xt, const unsigned* __restrict__ wbf,
    float* __restrict__ out, float* __restrict__ pst, int cbase, int bid,
    unsigned char* xs, float (*red1)[2][2][16], float (*red2)[2][2][16]) {
    constexpr int TAPS = KH * KW;
    constexpr int HB = 4;
    constexpr int ROWS = HB + KH - 1;
    constexpr int TOT = ROWS * RSTR;
    constexpr int NCH = (TOT + 1023) >> 10;   // 50 (KH=3) / 33 (KH=1)
    const int hb = bid & 15, n = bid >> 4;
    const int h0 = hb * HB;
    const int tid = threadIdx.x;
    const int lane = tid & 63;
    const int wv = tid >> 6;
    const int rh = wv >> 1, wn = wv & 1;  // wave = (row-half, w-half)
    const int l31 = lane & 31, hi = lane >> 5;
    const int wcol = wn * 32 + l31;

    // DMA-stage ROWS rows (contiguous span, pre-transposed, halos pre-zeroed)
    {
        const unsigned char* src = xt +
            (size_t)(n * 66 + h0 + (KH == 1 ? 1 : 0)) * RSTR + lane * 16;
#pragma unroll
        for (int c = wv; c < NCH; c += 4)
            gload_lds16(src + (c << 10), xs + (c << 10));
    }

    // A base: frag f=kk*2+hi, row l31 (+32): wp[t*512 + f*64 + row]
    const frag8* wp = (const frag8*)wbf + (size_t)n * TAPS * 512 + hi * 64 + l31;

    frag8 aA[8], aB[8];
    LOADA(aA, 0);                          // in flight during staging wait
    __syncthreads();

    accf16 a00 = {}, a01 = {}, a10 = {}, a11 = {};   // a{o-half}{row}
#pragma unroll
    for (int t = 0; t < TAPS; t += 2) {
        if (t + 1 < TAPS) LOADA(aB, t + 1);
        TAPSTEP(t, aA);
        if (t + 2 < TAPS) LOADA(aA, t + 2);
        if (t + 1 < TAPS) TAPSTEP(t + 1, aB);
    }

    // C write: rows h0+rh*2, h0+rh*2+1; both o-halves
    {
        float* ob = out + (size_t)n * 256 * HW + (h0 + rh * 2) * 64 + wcol;
#pragma unroll
        for (int rg = 0; rg < 16; ++rg) {
            const int o = (rg & 3) + 8 * (rg >> 2) + 4 * hi;
            float* p0 = ob + (size_t)shuf_ch(cbase + o) * HW;
            p0[0]  = a00[rg];
            p0[64] = a01[rg];
            float* p1 = ob + (size_t)shuf_ch(cbase + 32 + o) * HW;
            p1[0]  = a10[rg];
            p1[64] = a11[rg];
        }
    }

    // BN partial sums
#pragma unroll
    for (int rg = 0; rg < 16; ++rg) {
        float u1 = a00[rg] + a01[rg];
        float u2 = a00[rg] * a00[rg] + a01[rg] * a01[rg];
        float w1 = a10[rg] + a11[rg];
        float w2 = a10[rg] * a10[rg] + a11[rg] * a11[rg];
#pragma unroll
        for (int off = 16; off; off >>= 1) {
            u1 += __shfl_down(u1, off, 32);
            u2 += __shfl_down(u2, off, 32);
            w1 += __shfl_down(w1, off, 32);
            w2 += __shfl_down(w2, off, 32);
        }
        if (l31 == 0) {
            red1[wv][0][hi][rg] = u1; red2[wv][0][hi][rg] = u2;
            red1[wv][1][hi][rg] = w1; red2[wv][1][hi][rg] = w2;
        }
    }
    __syncthreads();
    if (tid < 64) {
        const int rg = tid & 15, hi2 = (tid >> 4) & 1, wm2 = tid >> 5;
        float s1 = 0.f, s2 = 0.f;
#pragma unroll
        for (int v = 0; v < 4; ++v) {
            s1 += red1[v][wm2][hi2][rg];
            s2 += red2[v][wm2][hi2][rg];
        }
        const int o = wm2 * 32 + (rg & 3) + 8 * (rg >> 2) + 4 * hi2;
        const int slot = n * 16 + hb;
        pst[o * 1024 + slot] = s1;
        pst[o * 1024 + 512 + slot] = s2;
    }
}

__device__ __forceinline__ void s0_body(const float* __restrict__ x,
                                        float* __restrict__ out, int bid) {
    const int n = bid >> 4, c0 = (bid & 15) * 4, tid = threadIdx.x;
#pragma unroll
    for (int j = 0; j < 4; ++j) {
        const int c = c0 + j;
        const float4* s = (const float4*)(x + (size_t)(n * 256 + c) * HW);
        float4* d = (float4*)(out + (size_t)(n * 256 + shuf_ch(c)) * HW);
#pragma unroll
        for (int it = 0; it < 4; ++it) d[tid + it * 256] = s[tid + it * 256];
    }
}

__global__ void __launch_bounds__(256, 3) conv_all_kernel(
    const float* __restrict__ x, const unsigned char* __restrict__ xt,
    const unsigned* __restrict__ wsq, const unsigned* __restrict__ wver,
    const unsigned* __restrict__ whor,
    float* __restrict__ out, float* __restrict__ pst) {
    __shared__ __align__(16) unsigned char xs[6 * RSTR + 512];
    __shared__ float red1[4][2][2][16], red2[4][2][2][16];
    int bid = blockIdx.x;
    if (bid < 512)
        conv_body<3, 3, 1, 1>(xt, wsq, out, pst, 64, bid, xs, red1, red2);
    else if (bid < 1024)
        conv_body<3, 1, 1, 0>(xt + XT_BR, wver, out, pst + 65536, 128,
                              bid - 512, xs, red1, red2);
    else if (bid < 1536)
        conv_body<1, 3, 0, 1>(xt + 2 * XT_BR, whor, out, pst + 131072, 192,
                              bid - 1024, xs, red1, red2);
    else
        s0_body(x, out, bid - 1536);
}

// ---- 4. reduce BN partials -> scale/shift, all branches --------------------
__global__ void __launch_bounds__(256) bnstats_all_kernel(
    const float* __restrict__ pst,
    const float* __restrict__ g0, const float* __restrict__ b0,
    const float* __restrict__ g1, const float* __restrict__ b1,
    const float* __restrict__ g2, const float* __restrict__ b2,
    float* __restrict__ ss) {
    int br = blockIdx.x >> 6, o = blockIdx.x & 63, t = threadIdx.x;
    const float* gamma = (br == 0) ? g0 : (br == 1) ? g1 : g2;
    const float* beta  = (br == 0) ? b0 : (br == 1) ? b1 : b2;
    const float* p = pst + br * 65536 + o * 1024;
    float s1 = 0.f, s2 = 0.f;
    for (int i = t; i < 512; i += 256) {
        s1 += p[i];
        s2 += p[512 + i];
    }
#pragma unroll
    for (int off = 32; off; off >>= 1) {
        s1 += __shfl_down(s1, off, 64);
        s2 += __shfl_down(s2, off, 64);
    }
    __shared__ float r1[4], r2[4];
    if ((t & 63) == 0) { r1[t >> 6] = s1; r2[t >> 6] = s2; }
    __syncthreads();
    if (t == 0) {
        float S1 = r1[0] + r1[1] + r1[2] + r1[3];
        float S2 = r2[0] + r2[1] + r2[2] + r2[3];
        float mean = S1 * CNT_INV;
        float var = S2 * CNT_INV - mean * mean;
        float scale = rsqrtf(var + 1e-5f) * gamma[o];
        ss[br * 128 + o * 2 + 0] = scale;
        ss[br * 128 + o * 2 + 1] = beta[o] - mean * scale;
    }
}

// ---- 5. apply BN in-place on d_out, all branches ---------------------------
__global__ void __launch_bounds__(256) bn_all_kernel(float* __restrict__ out,
                                                     const float* __restrict__ ss) {
    int gbid = blockIdx.x;                // 3 * 8192
    int sub = gbid >> 13;
    int bid = gbid & 8191;
    int chunk = bid & 3;
    int n = (bid >> 2) & 31;
    int o = bid >> 7;
    float scale = ss[sub * 128 + o * 2], shift = ss[sub * 128 + o * 2 + 1];
    int c_out = shuf_ch(64 * (sub + 1) + o);
    float4* p = (float4*)(out + (size_t)(n * 256 + c_out) * HW) + chunk * 256 + threadIdx.x;
    float4 v = *p;
    v.x = fmaf(v.x, scale, shift);
    v.y = fmaf(v.y, scale, shift);
    v.z = fmaf(v.z, scale, shift);
    v.w = fmaf(v.w, scale, shift);
    *p = v;
}

extern "C" void kernel_launch(void* const* d_in, const int* in_sizes, int n_in,
                              void* d_out, int out_size, void* d_ws, size_t ws_size,
                              hipStream_t stream) {
    const float* x        = (const float*)d_in[0];
    const float* sq_att_w = (const float*)d_in[1];
    const float* sq_att_b = (const float*)d_in[2];
    const float* sq_w     = (const float*)d_in[3];
    const float* sq_g     = (const float*)d_in[4];
    const float* sq_b     = (const float*)d_in[5];
    const float* ver_att_w= (const float*)d_in[6];
    const float* ver_att_b= (const float*)d_in[7];
    const float* ver_w    = (const float*)d_in[8];
    const float* ver_g    = (const float*)d_in[9];
    const float* ver_b    = (const float*)d_in[10];
    const float* hor_att_w= (const float*)d_in[11];
    const float* hor_att_b= (const float*)d_in[12];
    const float* hor_w    = (const float*)d_in[13];
    const float* hor_g    = (const float*)d_in[14];
    const float* hor_b    = (const float*)d_in[15];
    float* out = (float*)d_out;
    float* ws = (float*)d_ws;

    float* pooled = ws + WS_POOLED;
    float* ss     = ws + WS_SS;
    float* pst    = ws + WS_PST;
    unsigned* wbf_sq  = (unsigned*)(ws + WS_WBF_SQ);
    unsigned* wbf_ver = (unsigned*)(ws + WS_WBF_VER);
    unsigned* wbf_hor = (unsigned*)(ws + WS_WBF_HOR);
    unsigned char* xt = (unsigned char*)(ws + WS_XT);

    prepass_kernel<<<768, 256, 0, stream>>>(x, xt, pooled);
    aggbf_all_kernel<<<3840, 256, 0, stream>>>(pooled,
                                               sq_att_w, sq_att_b,
                                               ver_att_w, ver_att_b,
                                               hor_att_w, hor_att_b,
                                               sq_w, ver_w, hor_w,
                                               wbf_sq, wbf_ver, wbf_hor);
    conv_all_kernel<<<2048, 256, 0, stream>>>(x, xt, wbf_sq, wbf_ver, wbf_hor,
                                              out, pst);
    bnstats_all_kernel<<<192, 256, 0, stream>>>(pst, sq_g, sq_b, ver_g, ver_b,
                                                hor_g, hor_b, ss);
    bn_all_kernel<<<24576, 256, 0, stream>>>(out, ss);
}